// Round 1
// baseline (378.149 us; speedup 1.0000x reference)
//
#include <hip/hip_runtime.h>
#include <hip/hip_bf16.h>

typedef unsigned short u16;
typedef __bf16 bf16x8 __attribute__((ext_vector_type(8)));
typedef float  f32x4  __attribute__((ext_vector_type(4)));
typedef u16    u16x8  __attribute__((ext_vector_type(8)));

__device__ __forceinline__ u16 f2bf(float f) {
    unsigned u = __float_as_uint(f);
    u = (u + 0x7fffu + ((u >> 16) & 1u)) >> 16;   // RNE
    return (u16)u;
}
__device__ __forceinline__ float bf2f(u16 h) {
    return __uint_as_float(((unsigned)h) << 16);
}

// ---------------------------------------------------------------- convert
__global__ __launch_bounds__(256) void cvt_bf16_kernel(
    const float* __restrict__ src, u16* __restrict__ dst, int n8)
{
    int i = blockIdx.x * 256 + threadIdx.x;
    if (i >= n8) return;
    const float4* s4 = (const float4*)src;
    float4 a = s4[2 * i], b = s4[2 * i + 1];
    u16x8 o;
    o[0] = f2bf(a.x); o[1] = f2bf(a.y); o[2] = f2bf(a.z); o[3] = f2bf(a.w);
    o[4] = f2bf(b.x); o[5] = f2bf(b.y); o[6] = f2bf(b.z); o[7] = f2bf(b.w);
    ((u16x8*)dst)[i] = o;
}

// ---------------------------------------------------------------- GEMM C = A*B^T
// A: [M][K] bf16, Bm: [N][K] bf16, C: [M][N] (bf16 or f32), all row-major.
// grid = (N/128, M/128, nbatch)
#define BM 128
#define BN 128
#define BK 32

__device__ __forceinline__ void gload_lds16(const void* g, void* l) {
    __builtin_amdgcn_global_load_lds(
        (__attribute__((address_space(1))) void*)g,
        (__attribute__((address_space(3))) void*)l, 16, 0, 0);
}

template<bool OUT_BF16, bool HAS_BIAS>
__global__ __launch_bounds__(256) void gemm_bt(
    const u16* __restrict__ A, const u16* __restrict__ Bm,
    const float* __restrict__ bias, void* __restrict__ C,
    int M, int N, int K, float scale,
    long long aBS, long long bBS, long long cBS)
{
    A  += (size_t)blockIdx.z * aBS;
    Bm += (size_t)blockIdx.z * bBS;

    const int m0 = blockIdx.y * BM;
    const int n0 = blockIdx.x * BN;
    const int tid  = threadIdx.x;
    const int lane = tid & 63;
    const int wave = tid >> 6;
    const int wm = wave >> 1, wn = wave & 1;

    __shared__ u16 sA[2][BM * BK];
    __shared__ u16 sB[2][BN * BK];

    // staging: wave w covers tile rows [w*32, w*32+32), 2 issues of 16 rows each
    const int srow = wave * 32 + (lane >> 2);   // + j*16
    const int skc  = (lane & 3) * 8;
    const u16* gA = A  + (size_t)(m0 + srow) * K + skc;
    const u16* gB = Bm + (size_t)(n0 + srow) * K + skc;
    const int ldsOff = (wave * 32) * BK;        // + j*16*BK

    f32x4 acc[4][4] = {};

    const int fr = lane & 15;     // fragment row/col
    const int kg = lane >> 4;     // k-group
    const int aoff = (wm * 64 + fr) * BK + kg * 8;
    const int boff = (wn * 64 + fr) * BK + kg * 8;

    const int NT = K / BK;

    auto stage = [&](int buf, int t) {
        const u16* ga = gA + (size_t)t * BK;
        const u16* gb = gB + (size_t)t * BK;
        #pragma unroll
        for (int j = 0; j < 2; ++j) {
            gload_lds16(ga + (size_t)j * 16 * K, &sA[buf][ldsOff + j * 16 * BK]);
            gload_lds16(gb + (size_t)j * 16 * K, &sB[buf][ldsOff + j * 16 * BK]);
        }
    };

    stage(0, 0);
    __syncthreads();
    int buf = 0;
    for (int t = 0; t < NT; ++t) {
        if (t + 1 < NT) stage(buf ^ 1, t + 1);

        bf16x8 aF[4], bF[4];
        const u16* sa = &sA[buf][0];
        const u16* sb = &sB[buf][0];
        #pragma unroll
        for (int r = 0; r < 4; ++r) aF[r] = *(const bf16x8*)&sa[aoff + r * 16 * BK];
        #pragma unroll
        for (int c = 0; c < 4; ++c) bF[c] = *(const bf16x8*)&sb[boff + c * 16 * BK];
        #pragma unroll
        for (int r = 0; r < 4; ++r)
            #pragma unroll
            for (int c = 0; c < 4; ++c)
                acc[r][c] = __builtin_amdgcn_mfma_f32_16x16x32_bf16(
                    aF[r], bF[c], acc[r][c], 0, 0, 0);

        __syncthreads();
        buf ^= 1;
    }

    // epilogue: C[m][n], row = m0+wm*64+r*16+kg*4+q, col = n0+wn*64+c*16+fr
    if (OUT_BF16) {
        u16* Cb = (u16*)C + (size_t)blockIdx.z * cBS;
        #pragma unroll
        for (int r = 0; r < 4; ++r) {
            const int row0 = m0 + wm * 64 + r * 16 + kg * 4;
            #pragma unroll
            for (int c = 0; c < 4; ++c) {
                const int col = n0 + wn * 64 + c * 16 + fr;
                const float badd = HAS_BIAS ? bias[col] : 0.0f;
                f32x4 v = acc[r][c];
                #pragma unroll
                for (int q = 0; q < 4; ++q)
                    Cb[(size_t)(row0 + q) * N + col] = f2bf(v[q] * scale + badd);
            }
        }
    } else {
        float* Cf = (float*)C + (size_t)blockIdx.z * cBS;
        #pragma unroll
        for (int r = 0; r < 4; ++r) {
            const int row0 = m0 + wm * 64 + r * 16 + kg * 4;
            #pragma unroll
            for (int c = 0; c < 4; ++c) {
                const int col = n0 + wn * 64 + c * 16 + fr;
                const float badd = HAS_BIAS ? bias[col] : 0.0f;
                f32x4 v = acc[r][c];
                #pragma unroll
                for (int q = 0; q < 4; ++q)
                    Cf[(size_t)(row0 + q) * N + col] = v[q] * scale + badd;
            }
        }
    }
}

// ---------------------------------------------------------------- V transpose
// V: [B][2048][1024] -> Vt: [B][1024][2048], bf16, 64x64 LDS tiles
__global__ __launch_bounds__(256) void transpose_bf16(
    const u16* __restrict__ V, u16* __restrict__ Vt)
{
    __shared__ u16 tile[64][72];
    const int b  = blockIdx.z;
    const int k0 = blockIdx.y * 64;
    const int d0 = blockIdx.x * 64;
    const int tr = threadIdx.x >> 3;        // 0..31
    const int tc = (threadIdx.x & 7) * 8;   // 0..56

    const u16* src = V + ((size_t)b * 2048 + k0) * 1024 + d0;
    #pragma unroll
    for (int i = 0; i < 2; ++i) {
        int r = tr + i * 32;                // k-local
        *(u16x8*)&tile[r][tc] = *(const u16x8*)&src[(size_t)r * 1024 + tc];
    }
    __syncthreads();
    u16* dst = Vt + ((size_t)b * 1024 + d0) * 2048 + k0;
    #pragma unroll
    for (int i = 0; i < 2; ++i) {
        int r = tr + i * 32;                // d-local
        u16x8 o;
        #pragma unroll
        for (int j = 0; j < 8; ++j) o[j] = tile[tc + j][r];
        *(u16x8*)&dst[(size_t)r * 2048 + tc] = o;
    }
}

// ---------------------------------------------------------------- softmax (in-place, bf16)
// one block (256 thr) per row of 2048
__global__ __launch_bounds__(256) void softmax_kernel(u16* __restrict__ SP)
{
    const size_t row = blockIdx.x;
    u16x8* rp = (u16x8*)(SP + row * 2048);
    const int tid  = threadIdx.x;
    const int lane = tid & 63;
    const int wv   = tid >> 6;

    u16x8 v = rp[tid];
    float f[8];
    #pragma unroll
    for (int j = 0; j < 8; ++j) f[j] = bf2f(v[j]);

    float m = f[0];
    #pragma unroll
    for (int j = 1; j < 8; ++j) m = fmaxf(m, f[j]);
    #pragma unroll
    for (int o = 32; o; o >>= 1) m = fmaxf(m, __shfl_xor(m, o, 64));

    __shared__ float red[8];
    if (lane == 0) red[wv] = m;
    __syncthreads();
    m = fmaxf(fmaxf(red[0], red[1]), fmaxf(red[2], red[3]));

    float e[8], s = 0.f;
    #pragma unroll
    for (int j = 0; j < 8; ++j) { e[j] = __expf(f[j] - m); s += e[j]; }
    #pragma unroll
    for (int o = 32; o; o >>= 1) s += __shfl_xor(s, o, 64);
    if (lane == 0) red[4 + wv] = s;
    __syncthreads();
    s = (red[4] + red[5]) + (red[6] + red[7]);
    const float inv = 1.0f / s;

    u16x8 o8;
    #pragma unroll
    for (int j = 0; j < 8; ++j) o8[j] = f2bf(e[j] * inv);
    rp[tid] = o8;
}

// ---------------------------------------------------------------- launch
extern "C" void kernel_launch(void* const* d_in, const int* in_sizes, int n_in,
                              void* d_out, int out_size, void* d_ws, size_t ws_size,
                              hipStream_t stream)
{
    const int Bn = 4, S = 2048, D = 1024;
    const size_t nx = (size_t)Bn * S * D;   // 8388608
    const size_t nw = (size_t)D * D;

    const float* x  = (const float*)d_in[0];
    const float* y  = (const float*)d_in[1];
    const float* z  = (const float*)d_in[2];
    const float* Wq = (const float*)d_in[3];
    const float* bq = (const float*)d_in[4];
    const float* Wk = (const float*)d_in[5];
    const float* bk = (const float*)d_in[6];
    const float* Wv = (const float*)d_in[7];
    const float* bv = (const float*)d_in[8];

    u16* xb  = (u16*)d_ws;
    u16* yb  = xb + nx;
    u16* zb  = yb + nx;
    u16* wqb = zb + nx;
    u16* wkb = wqb + nw;
    u16* wvb = wkb + nw;
    u16* Qb  = wvb + nw;
    u16* Kb  = Qb + nx;
    u16* Vb  = Kb + nx;
    u16* Vt  = Vb + nx;
    u16* Pb  = xb;          // P [B][S][S] = 2*nx, aliases xb+yb (dead after Q/K GEMMs)

    const int n8x = (int)(nx / 8), n8w = (int)(nw / 8);
    cvt_bf16_kernel<<<(n8x + 255) / 256, 256, 0, stream>>>(x, xb, n8x);
    cvt_bf16_kernel<<<(n8x + 255) / 256, 256, 0, stream>>>(y, yb, n8x);
    cvt_bf16_kernel<<<(n8x + 255) / 256, 256, 0, stream>>>(z, zb, n8x);
    cvt_bf16_kernel<<<(n8w + 255) / 256, 256, 0, stream>>>(Wq, wqb, n8w);
    cvt_bf16_kernel<<<(n8w + 255) / 256, 256, 0, stream>>>(Wk, wkb, n8w);
    cvt_bf16_kernel<<<(n8w + 255) / 256, 256, 0, stream>>>(Wv, wvb, n8w);

    dim3 gQKV(D / BN, (Bn * S) / BM, 1);
    gemm_bt<true, true><<<gQKV, 256, 0, stream>>>(xb, wqb, bq, Qb, Bn * S, D, D, 1.0f, 0, 0, 0);
    gemm_bt<true, true><<<gQKV, 256, 0, stream>>>(yb, wkb, bk, Kb, Bn * S, D, D, 1.0f, 0, 0, 0);
    gemm_bt<true, true><<<gQKV, 256, 0, stream>>>(zb, wvb, bv, Vb, Bn * S, D, D, 1.0f, 0, 0, 0);

    transpose_bf16<<<dim3(D / 64, S / 64, Bn), 256, 0, stream>>>(Vb, Vt);

    // scores: P = (Q K^T) / 32, bf16
    gemm_bt<true, false><<<dim3(S / BN, S / BM, Bn), 256, 0, stream>>>(
        Qb, Kb, nullptr, Pb, S, S, D, 0.03125f,
        (long long)S * D, (long long)S * D, (long long)S * S);

    softmax_kernel<<<Bn * S, 256, 0, stream>>>(Pb);

    // out = P @ V  (via Vt), fp32
    gemm_bt<false, false><<<dim3(D / BN, S / BM, Bn), 256, 0, stream>>>(
        Pb, Vt, nullptr, d_out, S, D, S, 1.0f,
        (long long)S * S, (long long)D * S, (long long)S * D);
}

// Round 2
// 351.976 us; speedup vs baseline: 1.0744x; 1.0744x over previous
//
#include <hip/hip_runtime.h>
#include <hip/hip_bf16.h>

typedef unsigned short u16;
typedef __bf16 bf16x8 __attribute__((ext_vector_type(8)));
typedef float  f32x4  __attribute__((ext_vector_type(4)));
typedef u16    u16x8  __attribute__((ext_vector_type(8)));

__device__ __forceinline__ u16 f2bf(float f) {
    unsigned u = __float_as_uint(f);
    u = (u + 0x7fffu + ((u >> 16) & 1u)) >> 16;   // RNE
    return (u16)u;
}
__device__ __forceinline__ float bf2f(u16 h) {
    return __uint_as_float(((unsigned)h) << 16);
}

// ---------------------------------------------------------------- convert
__global__ __launch_bounds__(256) void cvt_bf16_kernel(
    const float* __restrict__ src, u16* __restrict__ dst, int n8)
{
    int i = blockIdx.x * 256 + threadIdx.x;
    if (i >= n8) return;
    const float4* s4 = (const float4*)src;
    float4 a = s4[2 * i], b = s4[2 * i + 1];
    u16x8 o;
    o[0] = f2bf(a.x); o[1] = f2bf(a.y); o[2] = f2bf(a.z); o[3] = f2bf(a.w);
    o[4] = f2bf(b.x); o[5] = f2bf(b.y); o[6] = f2bf(b.z); o[7] = f2bf(b.w);
    ((u16x8*)dst)[i] = o;
}

// ---------------------------------------------------------------- GEMM C = A*B^T
// 8-phase-style template: BM=256, BN=128, BK=64, 8 waves (2M x 4N),
// per-wave out 128x32, 2 phases/K-tile x 16 MFMA, 3 LDS buffers (144KB),
// prefetch distance 2 K-tiles, counted vmcnt(6), T2 XOR-swizzle, T5 setprio.
#define BMM 256
#define BNN 128
#define BKK 64
#define BUFU 24576        // u16 per buffer: A 256*64=16384 + B 128*64=8192
#define LDSB (3 * BUFU * 2)  // 147456 bytes

__device__ __forceinline__ void gload_lds16(const void* g, void* l) {
    __builtin_amdgcn_global_load_lds(
        (__attribute__((address_space(1))) void*)g,
        (__attribute__((address_space(3))) void*)l, 16, 0, 0);
}

template<bool OUT_BF16, bool HAS_BIAS>
__global__ __launch_bounds__(512, 2) void gemm8p(
    const u16* __restrict__ A, const u16* __restrict__ Bm,
    const float* __restrict__ bias, void* __restrict__ C,
    int M, int N, int K, float scale,
    long long aBS, long long bBS, long long cBS)
{
    extern __shared__ u16 lds[];
    A  += (size_t)blockIdx.z * aBS;
    Bm += (size_t)blockIdx.z * bBS;

    const int m0 = blockIdx.y * BMM;
    const int n0 = blockIdx.x * BNN;
    const int tid  = threadIdx.x;
    const int lane = tid & 63;
    const int wave = tid >> 6;          // 0..7
    const int wm   = wave >> 2;         // 0..1
    const int wn   = wave & 3;          // 0..3
    const int fr   = lane & 15;
    const int kg   = lane >> 4;         // 0..3

    // ---- staging addressing (T2: linear LDS dest + inverse-swizzled source)
    const int sl_a = lane >> 3;              // sub-row 0..7 within wave's 8 rows
    const int swsl = (lane & 7) ^ sl_a;      // swizzled 16B slot for source
    const u16* gAs = A  + (size_t)(m0 + wave * 8 + sl_a) * K + swsl * 8;
    const u16* gBs = Bm + (size_t)(n0 + wave * 8 + sl_a) * K + swsl * 8;
    const int ldsW = wave * 512;             // u16

    auto stageA = [&](u16* wbase, size_t gc, int i) {
        gload_lds16(gAs + gc + (size_t)i * 64 * K, wbase + i * 4096 + ldsW);
    };
    auto stageB = [&](u16* wbase, size_t gc, int i) {
        gload_lds16(gBs + gc + (size_t)i * 64 * K, wbase + 16384 + i * 4096 + ldsW);
    };

    f32x4 acc[8][2] = {};

    const int NT = K / BKK;
    const int swz = fr & 7;   // XOR on 16B-slot index at read time

    // ---- prologue: stage tiles 0 (buf0) and 1 (buf1); wait tile0; 6 in flight
    {
        u16* b0 = lds;
        u16* b1 = lds + BUFU;
        #pragma unroll
        for (int i = 0; i < 4; ++i) stageA(b0, 0, i);
        #pragma unroll
        for (int i = 0; i < 2; ++i) stageB(b0, 0, i);
        #pragma unroll
        for (int i = 0; i < 4; ++i) stageA(b1, BKK, i);
        #pragma unroll
        for (int i = 0; i < 2; ++i) stageB(b1, BKK, i);
        asm volatile("s_waitcnt vmcnt(6)" ::: "memory");
        __builtin_amdgcn_s_barrier();
    }

    int br = 0, bw = 2;
    for (int t = 0; t < NT; ++t) {
        const u16* sa = lds + br * BUFU;
        const u16* sb = sa + 16384;
        u16* wbase = lds + bw * BUFU;
        const bool st = (t + 2 < NT);
        const size_t gc = (size_t)(t + 2) * BKK;

        // ================= phase 0 (quadrant qm=0) =================
        bf16x8 bF[2][2];
        #pragma unroll
        for (int n = 0; n < 2; ++n)
            #pragma unroll
            for (int ks = 0; ks < 2; ++ks)
                bF[n][ks] = *(const bf16x8*)&sb[(wn * 32 + n * 16 + fr) * 64
                                + ((((ks << 2) | kg) ^ swz) << 3)];
        bf16x8 aF0[4][2];
        #pragma unroll
        for (int m = 0; m < 4; ++m)
            #pragma unroll
            for (int ks = 0; ks < 2; ++ks)
                aF0[m][ks] = *(const bf16x8*)&sa[(wm * 128 + m * 16 + fr) * 64
                                + ((((ks << 2) | kg) ^ swz) << 3)];
        if (st) { stageA(wbase, gc, 0); stageA(wbase, gc, 1); stageB(wbase, gc, 0); }
        __builtin_amdgcn_s_barrier();
        __builtin_amdgcn_s_setprio(1);
        #pragma unroll
        for (int m = 0; m < 4; ++m)
            #pragma unroll
            for (int n = 0; n < 2; ++n)
                #pragma unroll
                for (int ks = 0; ks < 2; ++ks)
                    acc[m][n] = __builtin_amdgcn_mfma_f32_16x16x32_bf16(
                        aF0[m][ks], bF[n][ks], acc[m][n], 0, 0, 0);
        __builtin_amdgcn_s_setprio(0);
        __builtin_amdgcn_s_barrier();

        // ================= phase 1 (quadrant qm=1) =================
        bf16x8 aF1[4][2];
        #pragma unroll
        for (int m = 0; m < 4; ++m)
            #pragma unroll
            for (int ks = 0; ks < 2; ++ks)
                aF1[m][ks] = *(const bf16x8*)&sa[(wm * 128 + 64 + m * 16 + fr) * 64
                                + ((((ks << 2) | kg) ^ swz) << 3)];
        if (st) { stageA(wbase, gc, 2); stageA(wbase, gc, 3); stageB(wbase, gc, 1); }
        if (st) asm volatile("s_waitcnt vmcnt(6)" ::: "memory");
        else    asm volatile("s_waitcnt vmcnt(0)" ::: "memory");
        __builtin_amdgcn_s_barrier();
        __builtin_amdgcn_s_setprio(1);
        #pragma unroll
        for (int m = 0; m < 4; ++m)
            #pragma unroll
            for (int n = 0; n < 2; ++n)
                #pragma unroll
                for (int ks = 0; ks < 2; ++ks)
                    acc[4 + m][n] = __builtin_amdgcn_mfma_f32_16x16x32_bf16(
                        aF1[m][ks], bF[n][ks], acc[4 + m][n], 0, 0, 0);
        __builtin_amdgcn_s_setprio(0);
        __builtin_amdgcn_s_barrier();

        br = (br == 2) ? 0 : br + 1;
        bw = (bw == 2) ? 0 : bw + 1;
    }

    // ---- epilogue: row = m0+wm*128+mi*16+kg*4+q, col = n0+wn*32+n*16+fr
    if (OUT_BF16) {
        u16* Cb = (u16*)C + (size_t)blockIdx.z * cBS;
        #pragma unroll
        for (int mi = 0; mi < 8; ++mi) {
            const int row0 = m0 + wm * 128 + mi * 16 + kg * 4;
            #pragma unroll
            for (int n = 0; n < 2; ++n) {
                const int col = n0 + wn * 32 + n * 16 + fr;
                const float badd = HAS_BIAS ? bias[col] : 0.0f;
                f32x4 v = acc[mi][n];
                #pragma unroll
                for (int q = 0; q < 4; ++q)
                    Cb[(size_t)(row0 + q) * N + col] = f2bf(v[q] * scale + badd);
            }
        }
    } else {
        float* Cf = (float*)C + (size_t)blockIdx.z * cBS;
        #pragma unroll
        for (int mi = 0; mi < 8; ++mi) {
            const int row0 = m0 + wm * 128 + mi * 16 + kg * 4;
            #pragma unroll
            for (int n = 0; n < 2; ++n) {
                const int col = n0 + wn * 32 + n * 16 + fr;
                const float badd = HAS_BIAS ? bias[col] : 0.0f;
                f32x4 v = acc[mi][n];
                #pragma unroll
                for (int q = 0; q < 4; ++q)
                    Cf[(size_t)(row0 + q) * N + col] = v[q] * scale + badd;
            }
        }
    }
}

// ---------------------------------------------------------------- V transpose
__global__ __launch_bounds__(256) void transpose_bf16(
    const u16* __restrict__ V, u16* __restrict__ Vt)
{
    __shared__ u16 tile[64][72];
    const int b  = blockIdx.z;
    const int k0 = blockIdx.y * 64;
    const int d0 = blockIdx.x * 64;
    const int tr = threadIdx.x >> 3;
    const int tc = (threadIdx.x & 7) * 8;

    const u16* src = V + ((size_t)b * 2048 + k0) * 1024 + d0;
    #pragma unroll
    for (int i = 0; i < 2; ++i) {
        int r = tr + i * 32;
        *(u16x8*)&tile[r][tc] = *(const u16x8*)&src[(size_t)r * 1024 + tc];
    }
    __syncthreads();
    u16* dst = Vt + ((size_t)b * 1024 + d0) * 2048 + k0;
    #pragma unroll
    for (int i = 0; i < 2; ++i) {
        int r = tr + i * 32;
        u16x8 o;
        #pragma unroll
        for (int j = 0; j < 8; ++j) o[j] = tile[tc + j][r];
        *(u16x8*)&dst[(size_t)r * 2048 + tc] = o;
    }
}

// ---------------------------------------------------------------- softmax (in-place, bf16)
__global__ __launch_bounds__(256) void softmax_kernel(u16* __restrict__ SP)
{
    const size_t row = blockIdx.x;
    u16x8* rp = (u16x8*)(SP + row * 2048);
    const int tid  = threadIdx.x;
    const int lane = tid & 63;
    const int wv   = tid >> 6;

    u16x8 v = rp[tid];
    float f[8];
    #pragma unroll
    for (int j = 0; j < 8; ++j) f[j] = bf2f(v[j]);

    float m = f[0];
    #pragma unroll
    for (int j = 1; j < 8; ++j) m = fmaxf(m, f[j]);
    #pragma unroll
    for (int o = 32; o; o >>= 1) m = fmaxf(m, __shfl_xor(m, o, 64));

    __shared__ float red[8];
    if (lane == 0) red[wv] = m;
    __syncthreads();
    m = fmaxf(fmaxf(red[0], red[1]), fmaxf(red[2], red[3]));

    float e[8], s = 0.f;
    #pragma unroll
    for (int j = 0; j < 8; ++j) { e[j] = __expf(f[j] - m); s += e[j]; }
    #pragma unroll
    for (int o = 32; o; o >>= 1) s += __shfl_xor(s, o, 64);
    if (lane == 0) red[4 + wv] = s;
    __syncthreads();
    s = (red[4] + red[5]) + (red[6] + red[7]);
    const float inv = 1.0f / s;

    u16x8 o8;
    #pragma unroll
    for (int j = 0; j < 8; ++j) o8[j] = f2bf(e[j] * inv);
    rp[tid] = o8;
}

// ---------------------------------------------------------------- launch
extern "C" void kernel_launch(void* const* d_in, const int* in_sizes, int n_in,
                              void* d_out, int out_size, void* d_ws, size_t ws_size,
                              hipStream_t stream)
{
    const int Bn = 4, S = 2048, D = 1024;
    const size_t nx = (size_t)Bn * S * D;
    const size_t nw = (size_t)D * D;

    const float* x  = (const float*)d_in[0];
    const float* y  = (const float*)d_in[1];
    const float* z  = (const float*)d_in[2];
    const float* Wq = (const float*)d_in[3];
    const float* bq = (const float*)d_in[4];
    const float* Wk = (const float*)d_in[5];
    const float* bk = (const float*)d_in[6];
    const float* Wv = (const float*)d_in[7];
    const float* bv = (const float*)d_in[8];

    u16* xb  = (u16*)d_ws;
    u16* yb  = xb + nx;
    u16* zb  = yb + nx;
    u16* wqb = zb + nx;
    u16* wkb = wqb + nw;
    u16* wvb = wkb + nw;
    u16* Qb  = wvb + nw;
    u16* Kb  = Qb + nx;
    u16* Vb  = Kb + nx;
    u16* Vt  = Vb + nx;
    u16* Pb  = xb;          // P [B][S][S] aliases xb+yb (dead after Q/K GEMMs)

    hipFuncSetAttribute((const void*)gemm8p<true,  true >,
                        hipFuncAttributeMaxDynamicSharedMemorySize, LDSB);
    hipFuncSetAttribute((const void*)gemm8p<true,  false>,
                        hipFuncAttributeMaxDynamicSharedMemorySize, LDSB);
    hipFuncSetAttribute((const void*)gemm8p<false, false>,
                        hipFuncAttributeMaxDynamicSharedMemorySize, LDSB);

    const int n8x = (int)(nx / 8), n8w = (int)(nw / 8);
    cvt_bf16_kernel<<<(n8x + 255) / 256, 256, 0, stream>>>(x, xb, n8x);
    cvt_bf16_kernel<<<(n8x + 255) / 256, 256, 0, stream>>>(y, yb, n8x);
    cvt_bf16_kernel<<<(n8x + 255) / 256, 256, 0, stream>>>(z, zb, n8x);
    cvt_bf16_kernel<<<(n8w + 255) / 256, 256, 0, stream>>>(Wq, wqb, n8w);
    cvt_bf16_kernel<<<(n8w + 255) / 256, 256, 0, stream>>>(Wk, wkb, n8w);
    cvt_bf16_kernel<<<(n8w + 255) / 256, 256, 0, stream>>>(Wv, wvb, n8w);

    dim3 gQKV(D / BNN, (Bn * S) / BMM, 1);
    gemm8p<true, true><<<gQKV, 512, LDSB, stream>>>(xb, wqb, bq, Qb, Bn * S, D, D, 1.0f, 0, 0, 0);
    gemm8p<true, true><<<gQKV, 512, LDSB, stream>>>(yb, wkb, bk, Kb, Bn * S, D, D, 1.0f, 0, 0, 0);
    gemm8p<true, true><<<gQKV, 512, LDSB, stream>>>(zb, wvb, bv, Vb, Bn * S, D, D, 1.0f, 0, 0, 0);

    transpose_bf16<<<dim3(D / 64, S / 64, Bn), 256, 0, stream>>>(Vb, Vt);

    gemm8p<true, false><<<dim3(S / BNN, S / BMM, Bn), 512, LDSB, stream>>>(
        Qb, Kb, nullptr, Pb, S, S, D, 0.03125f,
        (long long)S * D, (long long)S * D, (long long)S * S);

    softmax_kernel<<<Bn * S, 256, 0, stream>>>(Pb);

    gemm8p<false, false><<<dim3(D / BNN, S / BMM, Bn), 512, LDSB, stream>>>(
        Pb, Vt, nullptr, d_out, S, D, S, 1.0f,
        (long long)S * S, (long long)D * S, (long long)S * D);
}

// Round 3
// 346.416 us; speedup vs baseline: 1.0916x; 1.0160x over previous
//
#include <hip/hip_runtime.h>
#include <hip/hip_bf16.h>

typedef unsigned short u16;
typedef __bf16 bf16x8 __attribute__((ext_vector_type(8)));
typedef float  f32x4  __attribute__((ext_vector_type(4)));
typedef u16    u16x8  __attribute__((ext_vector_type(8)));

__device__ __forceinline__ u16 f2bf(float f) {
    unsigned u = __float_as_uint(f);
    u = (u + 0x7fffu + ((u >> 16) & 1u)) >> 16;   // RNE
    return (u16)u;
}
__device__ __forceinline__ float bf2f(u16 h) {
    return __uint_as_float(((unsigned)h) << 16);
}

// ---------------------------------------------------------------- convert
__global__ __launch_bounds__(256) void cvt_bf16_kernel(
    const float* __restrict__ src, u16* __restrict__ dst, int n8)
{
    int i = blockIdx.x * 256 + threadIdx.x;
    if (i >= n8) return;
    const float4* s4 = (const float4*)src;
    float4 a = s4[2 * i], b = s4[2 * i + 1];
    u16x8 o;
    o[0] = f2bf(a.x); o[1] = f2bf(a.y); o[2] = f2bf(a.z); o[3] = f2bf(a.w);
    o[4] = f2bf(b.x); o[5] = f2bf(b.y); o[6] = f2bf(b.z); o[7] = f2bf(b.w);
    ((u16x8*)dst)[i] = o;
}

// ---------------------------------------------------------------- GEMM C = A*B^T
// Pipelined template: BM=256, BN=128, BK=64, 8 waves (4M x 2N), wave tile
// 64x64, 2 phases/tile (ks0/ks1) x 16 MFMA, reads pipelined one phase ahead,
// 3 LDS buffers (144KB) distance-2, counted vmcnt(6), ONE barrier per tile,
// T2 XOR-swizzle (verified conflict-free), T5 setprio.
#define BUF_N 24576   // u16 per buffer: A 256*64=16384 + B 128*64=8192
#define LDS_N (3 * BUF_N * 2)  // 147456 bytes

__device__ __forceinline__ void gload_lds16(const void* g, void* l) {
    __builtin_amdgcn_global_load_lds(
        (__attribute__((address_space(1))) void*)g,
        (__attribute__((address_space(3))) void*)l, 16, 0, 0);
}

template<bool OUT_BF16, bool HAS_BIAS>
__global__ __launch_bounds__(512, 2) void gemm_p(
    const u16* __restrict__ A, const u16* __restrict__ Bm,
    const float* __restrict__ bias, void* __restrict__ C,
    int M, int N, int K, float scale,
    long long aBS, long long bBS, long long cBS)
{
    extern __shared__ u16 lds[];
    A  += (size_t)blockIdx.z * aBS;
    Bm += (size_t)blockIdx.z * bBS;

    const int m0 = blockIdx.y * 256;
    const int n0 = blockIdx.x * 128;
    const int tid  = threadIdx.x;
    const int lane = tid & 63;
    const int wave = tid >> 6;          // 0..7
    const int wm   = wave >> 1;         // 0..3  (64-row slice of A)
    const int wn   = wave & 1;          // 0..1  (64-row slice of B)
    const int fr   = lane & 15;
    const int kg   = lane >> 4;         // 0..3

    // ---- staging: each load covers 64 rows x 64 cols (8KB); linear LDS dest,
    // inverse-swizzled global source (rule #21).
    const int rl  = tid >> 3;                    // 0..63 row within chunk
    const int sw8 = ((tid & 7) ^ (rl & 7)) * 8;  // swizzled 16B slot (u16 units)
    const u16* gA = A  + (size_t)(m0 + rl) * K + sw8;
    const u16* gB = Bm + (size_t)(n0 + rl) * K + sw8;
    const int ldsW = wave * 512;                 // u16

    auto stA = [&](u16* bufb, int tk, int c) {   // c = 0..3
        gload_lds16(gA + (size_t)c * 64 * K + (size_t)tk * 64,
                    bufb + c * 4096 + ldsW);
    };
    auto stB = [&](u16* bufb, int tk, int c) {   // c = 0..1
        gload_lds16(gB + (size_t)c * 64 * K + (size_t)tk * 64,
                    bufb + 16384 + c * 4096 + ldsW);
    };

    // ---- fragment reads (swizzled slot)
    auto rdA = [&](const u16* sa, int m, int ks) {
        return *(const bf16x8*)&sa[(wm * 64 + m * 16 + fr) * 64
                                   + ((((ks << 2) | kg) ^ (fr & 7)) << 3)];
    };
    auto rdB = [&](const u16* sb, int n, int ks) {
        return *(const bf16x8*)&sb[(wn * 64 + n * 16 + fr) * 64
                                   + ((((ks << 2) | kg) ^ (fr & 7)) << 3)];
    };

    f32x4 acc[4][4] = {};
    bf16x8 a0[4], b0[4], a1[4], b1[4];
    const int NT = K / 64;

    u16 *p0 = lds, *p1 = lds + BUF_N, *p2 = lds + 2 * BUF_N;

    // ---- prologue: stage t0->p0, t1->p1; wait t0 (6 newest stay in flight)
    #pragma unroll
    for (int c = 0; c < 4; ++c) stA(p0, 0, c);
    #pragma unroll
    for (int c = 0; c < 2; ++c) stB(p0, 0, c);
    #pragma unroll
    for (int c = 0; c < 4; ++c) stA(p1, 1, c);
    #pragma unroll
    for (int c = 0; c < 2; ++c) stB(p1, 1, c);
    asm volatile("s_waitcnt vmcnt(6)" ::: "memory");
    __builtin_amdgcn_s_barrier();

    // preload phase-0 fragments of tile 0
    #pragma unroll
    for (int m = 0; m < 4; ++m) a0[m] = rdA(p0, m, 0);
    #pragma unroll
    for (int n = 0; n < 4; ++n) b0[n] = rdB(p0 + 16384, n, 0);

    for (int t = 0; t < NT; ++t) {
        const u16* sa = p0;
        const u16* sb = p0 + 16384;
        const bool st = (t + 2 < NT);

        // ========== phase 0: issue ks1 reads + all staging, MFMA ks0 ==========
        #pragma unroll
        for (int m = 0; m < 4; ++m) a1[m] = rdA(sa, m, 1);
        #pragma unroll
        for (int n = 0; n < 4; ++n) b1[n] = rdB(sb, n, 1);
        if (st) {
            #pragma unroll
            for (int c = 0; c < 4; ++c) stA(p2, t + 2, c);
            #pragma unroll
            for (int c = 0; c < 2; ++c) stB(p2, t + 2, c);
        }
        __builtin_amdgcn_s_setprio(1);
        #pragma unroll
        for (int m = 0; m < 4; ++m)
            #pragma unroll
            for (int n = 0; n < 4; ++n)
                acc[m][n] = __builtin_amdgcn_mfma_f32_16x16x32_bf16(
                    a0[m], b0[n], acc[m][n], 0, 0, 0);
        __builtin_amdgcn_s_setprio(0);

        // ========== phase 1: drain, counted vmcnt, barrier, next-tile reads,
        //            MFMA ks1 ==========
        asm volatile("s_waitcnt lgkmcnt(0)" ::: "memory");
        if (st) asm volatile("s_waitcnt vmcnt(6)" ::: "memory");
        else    asm volatile("s_waitcnt vmcnt(0)" ::: "memory");
        __builtin_amdgcn_s_barrier();
        if (t + 1 < NT) {
            const u16* na = p1;
            const u16* nb = p1 + 16384;
            #pragma unroll
            for (int m = 0; m < 4; ++m) a0[m] = rdA(na, m, 0);
            #pragma unroll
            for (int n = 0; n < 4; ++n) b0[n] = rdB(nb, n, 0);
        }
        __builtin_amdgcn_s_setprio(1);
        #pragma unroll
        for (int m = 0; m < 4; ++m)
            #pragma unroll
            for (int n = 0; n < 4; ++n)
                acc[m][n] = __builtin_amdgcn_mfma_f32_16x16x32_bf16(
                    a1[m], b1[n], acc[m][n], 0, 0, 0);
        __builtin_amdgcn_s_setprio(0);

        u16* tmp = p0; p0 = p1; p1 = p2; p2 = tmp;
    }

    // ---- epilogue: row = m0+wm*64+m*16+kg*4+q, col = n0+wn*64+n*16+fr
    if (OUT_BF16) {
        u16* Cb = (u16*)C + (size_t)blockIdx.z * cBS;
        #pragma unroll
        for (int m = 0; m < 4; ++m) {
            const int row0 = m0 + wm * 64 + m * 16 + kg * 4;
            #pragma unroll
            for (int n = 0; n < 4; ++n) {
                const int col = n0 + wn * 64 + n * 16 + fr;
                const float badd = HAS_BIAS ? bias[col] : 0.0f;
                f32x4 v = acc[m][n];
                #pragma unroll
                for (int q = 0; q < 4; ++q)
                    Cb[(size_t)(row0 + q) * N + col] = f2bf(v[q] * scale + badd);
            }
        }
    } else {
        float* Cf = (float*)C + (size_t)blockIdx.z * cBS;
        #pragma unroll
        for (int m = 0; m < 4; ++m) {
            const int row0 = m0 + wm * 64 + m * 16 + kg * 4;
            #pragma unroll
            for (int n = 0; n < 4; ++n) {
                const int col = n0 + wn * 64 + n * 16 + fr;
                const float badd = HAS_BIAS ? bias[col] : 0.0f;
                f32x4 v = acc[m][n];
                #pragma unroll
                for (int q = 0; q < 4; ++q)
                    Cf[(size_t)(row0 + q) * N + col] = v[q] * scale + badd;
            }
        }
    }
}

// ---------------------------------------------------------------- V transpose
__global__ __launch_bounds__(256) void transpose_bf16(
    const u16* __restrict__ V, u16* __restrict__ Vt)
{
    __shared__ u16 tile[64][72];
    const int b  = blockIdx.z;
    const int k0 = blockIdx.y * 64;
    const int d0 = blockIdx.x * 64;
    const int tr = threadIdx.x >> 3;
    const int tc = (threadIdx.x & 7) * 8;

    const u16* src = V + ((size_t)b * 2048 + k0) * 1024 + d0;
    #pragma unroll
    for (int i = 0; i < 2; ++i) {
        int r = tr + i * 32;
        *(u16x8*)&tile[r][tc] = *(const u16x8*)&src[(size_t)r * 1024 + tc];
    }
    __syncthreads();
    u16* dst = Vt + ((size_t)b * 1024 + d0) * 2048 + k0;
    #pragma unroll
    for (int i = 0; i < 2; ++i) {
        int r = tr + i * 32;
        u16x8 o;
        #pragma unroll
        for (int j = 0; j < 8; ++j) o[j] = tile[tc + j][r];
        *(u16x8*)&dst[(size_t)r * 2048 + tc] = o;
    }
}

// ---------------------------------------------------------------- softmax (in-place, bf16)
__global__ __launch_bounds__(256) void softmax_kernel(u16* __restrict__ SP)
{
    const size_t row = blockIdx.x;
    u16x8* rp = (u16x8*)(SP + row * 2048);
    const int tid  = threadIdx.x;
    const int lane = tid & 63;
    const int wv   = tid >> 6;

    u16x8 v = rp[tid];
    float f[8];
    #pragma unroll
    for (int j = 0; j < 8; ++j) f[j] = bf2f(v[j]);

    float m = f[0];
    #pragma unroll
    for (int j = 1; j < 8; ++j) m = fmaxf(m, f[j]);
    #pragma unroll
    for (int o = 32; o; o >>= 1) m = fmaxf(m, __shfl_xor(m, o, 64));

    __shared__ float red[8];
    if (lane == 0) red[wv] = m;
    __syncthreads();
    m = fmaxf(fmaxf(red[0], red[1]), fmaxf(red[2], red[3]));

    float e[8], s = 0.f;
    #pragma unroll
    for (int j = 0; j < 8; ++j) { e[j] = __expf(f[j] - m); s += e[j]; }
    #pragma unroll
    for (int o = 32; o; o >>= 1) s += __shfl_xor(s, o, 64);
    if (lane == 0) red[4 + wv] = s;
    __syncthreads();
    s = (red[4] + red[5]) + (red[6] + red[7]);
    const float inv = 1.0f / s;

    u16x8 o8;
    #pragma unroll
    for (int j = 0; j < 8; ++j) o8[j] = f2bf(e[j] * inv);
    rp[tid] = o8;
}

// ---------------------------------------------------------------- launch
extern "C" void kernel_launch(void* const* d_in, const int* in_sizes, int n_in,
                              void* d_out, int out_size, void* d_ws, size_t ws_size,
                              hipStream_t stream)
{
    const int Bn = 4, S = 2048, D = 1024;
    const size_t nx = (size_t)Bn * S * D;
    const size_t nw = (size_t)D * D;

    const float* x  = (const float*)d_in[0];
    const float* y  = (const float*)d_in[1];
    const float* z  = (const float*)d_in[2];
    const float* Wq = (const float*)d_in[3];
    const float* bq = (const float*)d_in[4];
    const float* Wk = (const float*)d_in[5];
    const float* bk = (const float*)d_in[6];
    const float* Wv = (const float*)d_in[7];
    const float* bv = (const float*)d_in[8];

    u16* xb  = (u16*)d_ws;
    u16* yb  = xb + nx;
    u16* zb  = yb + nx;
    u16* wqb = zb + nx;
    u16* wkb = wqb + nw;
    u16* wvb = wkb + nw;
    u16* Qb  = wvb + nw;
    u16* Kb  = Qb + nx;
    u16* Vb  = Kb + nx;
    u16* Vt  = Vb + nx;
    u16* Pb  = xb;          // P [B][S][S] aliases xb+yb (dead after Q/K GEMMs)

    hipFuncSetAttribute((const void*)gemm_p<true,  true >,
                        hipFuncAttributeMaxDynamicSharedMemorySize, LDS_N);
    hipFuncSetAttribute((const void*)gemm_p<true,  false>,
                        hipFuncAttributeMaxDynamicSharedMemorySize, LDS_N);
    hipFuncSetAttribute((const void*)gemm_p<false, false>,
                        hipFuncAttributeMaxDynamicSharedMemorySize, LDS_N);

    const int n8x = (int)(nx / 8), n8w = (int)(nw / 8);
    cvt_bf16_kernel<<<(n8x + 255) / 256, 256, 0, stream>>>(x, xb, n8x);
    cvt_bf16_kernel<<<(n8x + 255) / 256, 256, 0, stream>>>(y, yb, n8x);
    cvt_bf16_kernel<<<(n8x + 255) / 256, 256, 0, stream>>>(z, zb, n8x);
    cvt_bf16_kernel<<<(n8w + 255) / 256, 256, 0, stream>>>(Wq, wqb, n8w);
    cvt_bf16_kernel<<<(n8w + 255) / 256, 256, 0, stream>>>(Wk, wkb, n8w);
    cvt_bf16_kernel<<<(n8w + 255) / 256, 256, 0, stream>>>(Wv, wvb, n8w);

    dim3 gQKV(D / 128, (Bn * S) / 256, 1);       // 8 x 32 = 256 blocks
    gemm_p<true, true><<<gQKV, 512, LDS_N, stream>>>(xb, wqb, bq, Qb, Bn * S, D, D, 1.0f, 0, 0, 0);
    gemm_p<true, true><<<gQKV, 512, LDS_N, stream>>>(yb, wkb, bk, Kb, Bn * S, D, D, 1.0f, 0, 0, 0);
    gemm_p<true, true><<<gQKV, 512, LDS_N, stream>>>(zb, wvb, bv, Vb, Bn * S, D, D, 1.0f, 0, 0, 0);

    transpose_bf16<<<dim3(D / 64, S / 64, Bn), 256, 0, stream>>>(Vb, Vt);

    // scores: P = (Q K^T) / 32   (16 x 8 x 4 = 512 blocks)
    gemm_p<true, false><<<dim3(S / 128, S / 256, Bn), 512, LDS_N, stream>>>(
        Qb, Kb, nullptr, Pb, S, S, D, 0.03125f,
        (long long)S * D, (long long)S * D, (long long)S * S);

    softmax_kernel<<<Bn * S, 256, 0, stream>>>(Pb);

    // out = P @ V (via Vt), fp32   (8 x 8 x 4 = 256 blocks)
    gemm_p<false, false><<<dim3(D / 128, S / 256, Bn), 512, LDS_N, stream>>>(
        Pb, Vt, nullptr, d_out, S, D, S, 1.0f,
        (long long)S * S, (long long)D * S, (long long)S * D);
}

// Round 4
// 321.997 us; speedup vs baseline: 1.1744x; 1.0758x over previous
//
#include <hip/hip_runtime.h>
#include <hip/hip_bf16.h>

typedef unsigned short u16;
typedef __bf16 bf16x8 __attribute__((ext_vector_type(8)));
typedef float  f32x4  __attribute__((ext_vector_type(4)));
typedef u16    u16x8  __attribute__((ext_vector_type(8)));

__device__ __forceinline__ u16 f2bf(float f) {
    unsigned u = __float_as_uint(f);
    u = (u + 0x7fffu + ((u >> 16) & 1u)) >> 16;   // RNE
    return (u16)u;
}
__device__ __forceinline__ float bf2f(u16 h) {
    return __uint_as_float(((unsigned)h) << 16);
}

// ---------------------------------------------------------------- convert
__global__ __launch_bounds__(256) void cvt_bf16_kernel(
    const float* __restrict__ src, u16* __restrict__ dst, int n8)
{
    int i = blockIdx.x * 256 + threadIdx.x;
    if (i >= n8) return;
    const float4* s4 = (const float4*)src;
    float4 a = s4[2 * i], b = s4[2 * i + 1];
    u16x8 o;
    o[0] = f2bf(a.x); o[1] = f2bf(a.y); o[2] = f2bf(a.z); o[3] = f2bf(a.w);
    o[4] = f2bf(b.x); o[5] = f2bf(b.y); o[6] = f2bf(b.z); o[7] = f2bf(b.w);
    ((u16x8*)dst)[i] = o;
}

// ---------------------------------------------------------------- GEMM C = A*B^T
// R3 pipeline + T1 XCD swizzle with L2 group shaping.
// BM=256, BN=128, BK=64, 8 waves (4M x 2N), wave tile 64x64, reads pipelined
// one phase ahead, 3 LDS buffers (144KB) distance-2, counted vmcnt(6),
// ONE barrier per tile, T2 XOR-swizzle, T5 setprio.
// Requires: grid nwg % 8 == 0 and gridDim.y % 4 == 0 (all launches satisfy).
#define BUF_N 24576   // u16 per buffer: A 256*64=16384 + B 128*64=8192
#define LDS_N (3 * BUF_N * 2)  // 147456 bytes

__device__ __forceinline__ void gload_lds16(const void* g, void* l) {
    __builtin_amdgcn_global_load_lds(
        (__attribute__((address_space(1))) void*)g,
        (__attribute__((address_space(3))) void*)l, 16, 0, 0);
}

template<bool OUT_BF16, bool HAS_BIAS>
__global__ __launch_bounds__(512, 2) void gemm_p(
    const u16* __restrict__ A, const u16* __restrict__ Bm,
    const float* __restrict__ bias, void* __restrict__ C,
    int M, int N, int K, float scale,
    long long aBS, long long bBS, long long cBS)
{
    extern __shared__ u16 lds[];

    // ---- T1: XCD-aware remap + L2 group shaping (4 m-rows per group) ----
    const int gx = gridDim.x, gy = gridDim.y;
    const int slab = gx * gy;
    const int nwg  = slab * gridDim.z;
    const int b    = blockIdx.x + gx * (blockIdx.y + gy * blockIdx.z);
    const int qc   = nwg >> 3;
    const int L    = (b & 7) * qc + (b >> 3);    // same-XCD blocks -> consecutive L
    const int tz   = L / slab;
    const int rr   = L - tz * slab;
    const int g4   = rr / (gx * 4);
    const int w4   = rr - g4 * (gx * 4);
    const int tx   = w4 >> 2;                    // n-tile
    const int ty   = g4 * 4 + (w4 & 3);          // m-tile (m-minor within group)

    A  += (size_t)tz * aBS;
    Bm += (size_t)tz * bBS;

    const int m0 = ty * 256;
    const int n0 = tx * 128;
    const int tid  = threadIdx.x;
    const int lane = tid & 63;
    const int wave = tid >> 6;          // 0..7
    const int wm   = wave >> 1;         // 0..3  (64-row slice of A)
    const int wn   = wave & 1;          // 0..1  (64-row slice of B)
    const int fr   = lane & 15;
    const int kg   = lane >> 4;         // 0..3

    // ---- staging: linear LDS dest, inverse-swizzled global source (rule #21)
    const int rl  = tid >> 3;                    // 0..63 row within chunk
    const int sw8 = ((tid & 7) ^ (rl & 7)) * 8;  // swizzled 16B slot (u16 units)
    const u16* gA = A  + (size_t)(m0 + rl) * K + sw8;
    const u16* gB = Bm + (size_t)(n0 + rl) * K + sw8;
    const int ldsW = wave * 512;                 // u16

    auto stA = [&](u16* bufb, int tk, int c) {   // c = 0..3
        gload_lds16(gA + (size_t)c * 64 * K + (size_t)tk * 64,
                    bufb + c * 4096 + ldsW);
    };
    auto stB = [&](u16* bufb, int tk, int c) {   // c = 0..1
        gload_lds16(gB + (size_t)c * 64 * K + (size_t)tk * 64,
                    bufb + 16384 + c * 4096 + ldsW);
    };

    // ---- fragment reads (swizzled slot)
    auto rdA = [&](const u16* sa, int m, int ks) {
        return *(const bf16x8*)&sa[(wm * 64 + m * 16 + fr) * 64
                                   + ((((ks << 2) | kg) ^ (fr & 7)) << 3)];
    };
    auto rdB = [&](const u16* sb, int n, int ks) {
        return *(const bf16x8*)&sb[(wn * 64 + n * 16 + fr) * 64
                                   + ((((ks << 2) | kg) ^ (fr & 7)) << 3)];
    };

    f32x4 acc[4][4] = {};
    bf16x8 a0[4], b0[4], a1[4], b1[4];
    const int NT = K / 64;

    u16 *p0 = lds, *p1 = lds + BUF_N, *p2 = lds + 2 * BUF_N;

    // ---- prologue: stage t0->p0, t1->p1; wait t0 (6 newest stay in flight)
    #pragma unroll
    for (int c = 0; c < 4; ++c) stA(p0, 0, c);
    #pragma unroll
    for (int c = 0; c < 2; ++c) stB(p0, 0, c);
    #pragma unroll
    for (int c = 0; c < 4; ++c) stA(p1, 1, c);
    #pragma unroll
    for (int c = 0; c < 2; ++c) stB(p1, 1, c);
    asm volatile("s_waitcnt vmcnt(6)" ::: "memory");
    __builtin_amdgcn_s_barrier();

    // preload phase-0 fragments of tile 0
    #pragma unroll
    for (int m = 0; m < 4; ++m) a0[m] = rdA(p0, m, 0);
    #pragma unroll
    for (int n = 0; n < 4; ++n) b0[n] = rdB(p0 + 16384, n, 0);

    for (int t = 0; t < NT; ++t) {
        const u16* sa = p0;
        const u16* sb = p0 + 16384;
        const bool st = (t + 2 < NT);

        // ========== phase 0: issue ks1 reads + all staging, MFMA ks0 ==========
        #pragma unroll
        for (int m = 0; m < 4; ++m) a1[m] = rdA(sa, m, 1);
        #pragma unroll
        for (int n = 0; n < 4; ++n) b1[n] = rdB(sb, n, 1);
        if (st) {
            #pragma unroll
            for (int c = 0; c < 4; ++c) stA(p2, t + 2, c);
            #pragma unroll
            for (int c = 0; c < 2; ++c) stB(p2, t + 2, c);
        }
        __builtin_amdgcn_s_setprio(1);
        #pragma unroll
        for (int m = 0; m < 4; ++m)
            #pragma unroll
            for (int n = 0; n < 4; ++n)
                acc[m][n] = __builtin_amdgcn_mfma_f32_16x16x32_bf16(
                    a0[m], b0[n], acc[m][n], 0, 0, 0);
        __builtin_amdgcn_s_setprio(0);

        // ========== phase 1: drain, counted vmcnt, barrier, next-tile reads,
        //            MFMA ks1 ==========
        asm volatile("s_waitcnt lgkmcnt(0)" ::: "memory");
        if (st) asm volatile("s_waitcnt vmcnt(6)" ::: "memory");
        else    asm volatile("s_waitcnt vmcnt(0)" ::: "memory");
        __builtin_amdgcn_s_barrier();
        if (t + 1 < NT) {
            const u16* na = p1;
            const u16* nb = p1 + 16384;
            #pragma unroll
            for (int m = 0; m < 4; ++m) a0[m] = rdA(na, m, 0);
            #pragma unroll
            for (int n = 0; n < 4; ++n) b0[n] = rdB(nb, n, 0);
        }
        __builtin_amdgcn_s_setprio(1);
        #pragma unroll
        for (int m = 0; m < 4; ++m)
            #pragma unroll
            for (int n = 0; n < 4; ++n)
                acc[m][n] = __builtin_amdgcn_mfma_f32_16x16x32_bf16(
                    a1[m], b1[n], acc[m][n], 0, 0, 0);
        __builtin_amdgcn_s_setprio(0);

        u16* tmp = p0; p0 = p1; p1 = p2; p2 = tmp;
    }

    // ---- epilogue: row = m0+wm*64+m*16+kg*4+q, col = n0+wn*64+n*16+fr
    if (OUT_BF16) {
        u16* Cb = (u16*)C + (size_t)tz * cBS;
        #pragma unroll
        for (int m = 0; m < 4; ++m) {
            const int row0 = m0 + wm * 64 + m * 16 + kg * 4;
            #pragma unroll
            for (int n = 0; n < 4; ++n) {
                const int col = n0 + wn * 64 + n * 16 + fr;
                const float badd = HAS_BIAS ? bias[col] : 0.0f;
                f32x4 v = acc[m][n];
                #pragma unroll
                for (int q = 0; q < 4; ++q)
                    Cb[(size_t)(row0 + q) * N + col] = f2bf(v[q] * scale + badd);
            }
        }
    } else {
        float* Cf = (float*)C + (size_t)tz * cBS;
        #pragma unroll
        for (int m = 0; m < 4; ++m) {
            const int row0 = m0 + wm * 64 + m * 16 + kg * 4;
            #pragma unroll
            for (int n = 0; n < 4; ++n) {
                const int col = n0 + wn * 64 + n * 16 + fr;
                const float badd = HAS_BIAS ? bias[col] : 0.0f;
                f32x4 v = acc[m][n];
                #pragma unroll
                for (int q = 0; q < 4; ++q)
                    Cf[(size_t)(row0 + q) * N + col] = v[q] * scale + badd;
            }
        }
    }
}

// ---------------------------------------------------------------- V transpose
__global__ __launch_bounds__(256) void transpose_bf16(
    const u16* __restrict__ V, u16* __restrict__ Vt)
{
    __shared__ u16 tile[64][72];
    const int b  = blockIdx.z;
    const int k0 = blockIdx.y * 64;
    const int d0 = blockIdx.x * 64;
    const int tr = threadIdx.x >> 3;
    const int tc = (threadIdx.x & 7) * 8;

    const u16* src = V + ((size_t)b * 2048 + k0) * 1024 + d0;
    #pragma unroll
    for (int i = 0; i < 2; ++i) {
        int r = tr + i * 32;
        *(u16x8*)&tile[r][tc] = *(const u16x8*)&src[(size_t)r * 1024 + tc];
    }
    __syncthreads();
    u16* dst = Vt + ((size_t)b * 1024 + d0) * 2048 + k0;
    #pragma unroll
    for (int i = 0; i < 2; ++i) {
        int r = tr + i * 32;
        u16x8 o;
        #pragma unroll
        for (int j = 0; j < 8; ++j) o[j] = tile[tc + j][r];
        *(u16x8*)&dst[(size_t)r * 2048 + tc] = o;
    }
}

// ---------------------------------------------------------------- softmax (in-place, bf16)
__global__ __launch_bounds__(256) void softmax_kernel(u16* __restrict__ SP)
{
    const size_t row = blockIdx.x;
    u16x8* rp = (u16x8*)(SP + row * 2048);
    const int tid  = threadIdx.x;
    const int lane = tid & 63;
    const int wv   = tid >> 6;

    u16x8 v = rp[tid];
    float f[8];
    #pragma unroll
    for (int j = 0; j < 8; ++j) f[j] = bf2f(v[j]);

    float m = f[0];
    #pragma unroll
    for (int j = 1; j < 8; ++j) m = fmaxf(m, f[j]);
    #pragma unroll
    for (int o = 32; o; o >>= 1) m = fmaxf(m, __shfl_xor(m, o, 64));

    __shared__ float red[8];
    if (lane == 0) red[wv] = m;
    __syncthreads();
    m = fmaxf(fmaxf(red[0], red[1]), fmaxf(red[2], red[3]));

    float e[8], s = 0.f;
    #pragma unroll
    for (int j = 0; j < 8; ++j) { e[j] = __expf(f[j] - m); s += e[j]; }
    #pragma unroll
    for (int o = 32; o; o >>= 1) s += __shfl_xor(s, o, 64);
    if (lane == 0) red[4 + wv] = s;
    __syncthreads();
    s = (red[4] + red[5]) + (red[6] + red[7]);
    const float inv = 1.0f / s;

    u16x8 o8;
    #pragma unroll
    for (int j = 0; j < 8; ++j) o8[j] = f2bf(e[j] * inv);
    rp[tid] = o8;
}

// ---------------------------------------------------------------- launch
extern "C" void kernel_launch(void* const* d_in, const int* in_sizes, int n_in,
                              void* d_out, int out_size, void* d_ws, size_t ws_size,
                              hipStream_t stream)
{
    const int Bn = 4, S = 2048, D = 1024;
    const size_t nx = (size_t)Bn * S * D;
    const size_t nw = (size_t)D * D;

    const float* x  = (const float*)d_in[0];
    const float* y  = (const float*)d_in[1];
    const float* z  = (const float*)d_in[2];
    const float* Wq = (const float*)d_in[3];
    const float* bq = (const float*)d_in[4];
    const float* Wk = (const float*)d_in[5];
    const float* bk = (const float*)d_in[6];
    const float* Wv = (const float*)d_in[7];
    const float* bv = (const float*)d_in[8];

    u16* xb  = (u16*)d_ws;
    u16* yb  = xb + nx;
    u16* zb  = yb + nx;
    u16* wqb = zb + nx;
    u16* wkb = wqb + nw;
    u16* wvb = wkb + nw;
    u16* Qb  = wvb + nw;
    u16* Kb  = Qb + nx;
    u16* Vb  = Kb + nx;
    u16* Vt  = Vb + nx;
    u16* Pb  = xb;          // P [B][S][S] aliases xb+yb (dead after Q/K GEMMs)

    hipFuncSetAttribute((const void*)gemm_p<true,  true >,
                        hipFuncAttributeMaxDynamicSharedMemorySize, LDS_N);
    hipFuncSetAttribute((const void*)gemm_p<true,  false>,
                        hipFuncAttributeMaxDynamicSharedMemorySize, LDS_N);
    hipFuncSetAttribute((const void*)gemm_p<false, false>,
                        hipFuncAttributeMaxDynamicSharedMemorySize, LDS_N);

    const int n8x = (int)(nx / 8), n8w = (int)(nw / 8);
    cvt_bf16_kernel<<<(n8x + 255) / 256, 256, 0, stream>>>(x, xb, n8x);
    cvt_bf16_kernel<<<(n8x + 255) / 256, 256, 0, stream>>>(y, yb, n8x);
    cvt_bf16_kernel<<<(n8x + 255) / 256, 256, 0, stream>>>(z, zb, n8x);
    cvt_bf16_kernel<<<(n8w + 255) / 256, 256, 0, stream>>>(Wq, wqb, n8w);
    cvt_bf16_kernel<<<(n8w + 255) / 256, 256, 0, stream>>>(Wk, wkb, n8w);
    cvt_bf16_kernel<<<(n8w + 255) / 256, 256, 0, stream>>>(Wv, wvb, n8w);

    dim3 gQKV(D / 128, (Bn * S) / 256, 1);       // 8 x 32 = 256 blocks
    gemm_p<true, true><<<gQKV, 512, LDS_N, stream>>>(xb, wqb, bq, Qb, Bn * S, D, D, 1.0f, 0, 0, 0);
    gemm_p<true, true><<<gQKV, 512, LDS_N, stream>>>(yb, wkb, bk, Kb, Bn * S, D, D, 1.0f, 0, 0, 0);
    gemm_p<true, true><<<gQKV, 512, LDS_N, stream>>>(zb, wvb, bv, Vb, Bn * S, D, D, 1.0f, 0, 0, 0);

    transpose_bf16<<<dim3(D / 64, S / 64, Bn), 256, 0, stream>>>(Vb, Vt);

    // scores: P = (Q K^T) / 32   (16 x 8 x 4 = 512 blocks)
    gemm_p<true, false><<<dim3(S / 128, S / 256, Bn), 512, LDS_N, stream>>>(
        Qb, Kb, nullptr, Pb, S, S, D, 0.03125f,
        (long long)S * D, (long long)S * D, (long long)S * S);

    softmax_kernel<<<Bn * S, 256, 0, stream>>>(Pb);

    // out = P @ V (via Vt), fp32   (8 x 8 x 4 = 256 blocks)
    gemm_p<false, false><<<dim3(D / 128, S / 256, Bn), 512, LDS_N, stream>>>(
        Pb, Vt, nullptr, d_out, S, D, S, 1.0f,
        (long long)S * S, (long long)D * S, (long long)S * D);
}